// Round 14
// baseline (404.872 us; speedup 1.0000x reference)
//
#include <hip/hip_runtime.h>
#include <hip/hip_bf16.h>

typedef unsigned short u16;
typedef unsigned int u32;
typedef unsigned long long u64;
typedef __attribute__((ext_vector_type(8))) short short8;
typedef __attribute__((ext_vector_type(4))) float f32x4;

#define NB 32      // trees
#define NN 128     // nodes per tree
#define HH 300     // hidden
#define NV 32000   // vocab
#define KP 320     // padded K; hb16 row stride
#define KX 352     // padded RD+E
#define XGS 1280   // xg row stride

// scan: 32 trees x 15 slices, level-synchronous, MFMA MV
#define NSLICE 15
#define UPS 20
#define NROWS 80
#define GMAXN 16
#define LDW 328

#define TPB 512
#define SCANB (NB * NSLICE)   // 480 scan blocks
#define CASTB 128             // W_out cast blocks
#define GEMMB (125 * 32)      // 4000 gemm blocks (256-col tiles, nblk-major)

// scan smem offsets (bytes); gemm overlay: As@0 (10240), Bs@10240 (20480)
#define SM_WL 0
#define SM_HS 52480
#define SM_GATES 62976
#define SM_CL 68224
#define SM_NID 78544
#define SM_PAR 78608
#define SM_BYTES 78720

#define A_LD(p)     __hip_atomic_load((p), __ATOMIC_RELAXED, __HIP_MEMORY_SCOPE_AGENT)
#define A_ST(p, v)  __hip_atomic_store((p), (v), __ATOMIC_RELAXED, __HIP_MEMORY_SCOPE_AGENT)
#define A_ADD(p, v) __hip_atomic_fetch_add((p), (v), __ATOMIC_RELAXED, __HIP_MEMORY_SCOPE_AGENT)

__device__ __forceinline__ float sigm(float x) { return 1.f / (1.f + __expf(-x)); }
__device__ __forceinline__ float tanh_f(float x) {
    float e = __expf(2.f * x);
    return 1.f - 2.f / (e + 1.f);
}
__device__ __forceinline__ u16 f2bf(float f) {
    __hip_bfloat16 b = __float2bfloat16(f);
    return *reinterpret_cast<u16*>(&b);
}

// hb16: [B][129][320] bf16, slot 0 = root h; counters zeroed every launch
__global__ void k_init(const float* __restrict__ rh, u16* __restrict__ hb16,
                       int* __restrict__ lvl_done, int* __restrict__ tree_done,
                       int* __restrict__ cast_done) {
    const int stride = gridDim.x * blockDim.x;
    const int idx = blockIdx.x * blockDim.x + threadIdx.x;
    for (int e = idx; e < NB * 129 * 20; e += stride) {
        int row = e / 20, c = 300 + (e - row * 20);
        hb16[(size_t)row * KP + c] = 0;
    }
    for (int e = idx; e < NB * HH; e += stride) {
        int b = e / HH, u = e - b * HH;
        hb16[(size_t)(b * 129) * KP + u] = f2bf(rh[e]);
    }
    for (int e = idx; e < NB * NN; e += stride) lvl_done[e] = 0;
    if (idx < NB) tree_done[idx] = 0;
    if (idx == 0) cast_done[0] = 0;
}

// Wihp [1280][352] bf16; Wp16 [15][80][328] bf16 (scan W_hh slices)
__global__ void k_pack(const float* __restrict__ W_ih, const float* __restrict__ W_hh,
                       u16* __restrict__ Wihp, u16* __restrict__ Wp16) {
    const int tot = 1280 * KX + NSLICE * NROWS * LDW;
    for (int n = blockIdx.x * blockDim.x + threadIdx.x; n < tot; n += gridDim.x * blockDim.x) {
        if (n < 1280 * KX) {
            int r = n / KX, k = n - r * KX;
            float v = (r < 1200 && k < 350) ? W_ih[r * 350 + k] : 0.f;
            Wihp[n] = f2bf(v);
        } else {
            int m = n - 1280 * KX;
            int s = m / (NROWS * LDW);
            int rem = m - s * (NROWS * LDW);
            int r = rem / LDW, k = rem - r * LDW;
            int g = r / UPS, ul = r - g * UPS;
            int grow = g * HH + s * UPS + ul;
            float v = (k < HH) ? W_hh[grow * HH + k] : 0.f;
            Wp16[m] = f2bf(v);
        }
    }
}

// Xbf [4096][352] bf16 = concat(rel_emb[rel], emb[word], 0-pad)
__global__ void k_gatherX(const int* __restrict__ relations, const int* __restrict__ prev_words,
                          const float* __restrict__ rel_emb, const float* __restrict__ emb,
                          u16* __restrict__ X) {
    for (int e = blockIdx.x * blockDim.x + threadIdx.x; e < NB * NN * KX;
         e += gridDim.x * blockDim.x) {
        int node = e / KX, c = e - node * KX;
        float v = 0.f;
        if (c < 50) v = rel_emb[relations[node] * 50 + c];
        else if (c < 350) v = emb[(size_t)prev_words[node] * 300 + (c - 50)];
        X[e] = f2bf(v);
    }
}

// per-tree level schedule
__global__ void k_prep(const int* __restrict__ parents, int* __restrict__ lvl_nodes,
                       int* __restrict__ lvl_cnt, int* __restrict__ lvl_start,
                       int* __restrict__ nlev) {
    __shared__ int dep[NB][NN];
    __shared__ int cnt[NB][NN];
    __shared__ int st[NB][NN];
    const int t = threadIdx.x;
    if (t < NB) {
        for (int l = 0; l < NN; ++l) cnt[t][l] = 0;
        int md = 0;
        for (int i = 0; i < NN; ++i) {
            int p = parents[t * NN + i];
            int d = (p < 0) ? 0 : dep[t][p] + 1;
            dep[t][i] = d;
            cnt[t][d]++;
            md = max(md, d);
        }
        nlev[t] = md + 1;
        int run = 0;
        for (int l = 0; l < NN; ++l) {
            st[t][l] = run;
            lvl_start[t * NN + l] = run;
            lvl_cnt[t * NN + l] = cnt[t][l];
            run += cnt[t][l];
        }
        for (int i = 0; i < NN; ++i) {
            int d = dep[t][i];
            lvl_nodes[t * NN + st[t][d]] = i;
            st[t][d]++;
        }
    }
}

// xg[4096][1280] = X @ Wihp^T + b_ih (swapped-MFMA epilogue, f32x4 stores)
__global__ __launch_bounds__(256) void k_xgemm(const u16* __restrict__ Xbf,
                                               const u16* __restrict__ Wihp,
                                               const float* __restrict__ b_ih,
                                               float* __restrict__ xg) {
    __shared__ __align__(16) u16 As[128 * 40];
    __shared__ __align__(16) u16 Bs[128 * 40];
    const int tid = threadIdx.x;
    const int lane = tid & 63, wv = tid >> 6;
    const int wm = wv >> 1, wn = wv & 1;
    const int mblk = blockIdx.x, nblk = blockIdx.y;
    const u16* Ag = Xbf + (size_t)mblk * 128 * KX;
    const u16* Bg = Wihp + (size_t)nblk * 128 * KX;
    f32x4 acc[4][4] = {};
    const int lrow = lane & 15, lseg = lane >> 4;
    for (int kk = 0; kk < KX; kk += 32) {
#pragma unroll
        for (int q = 0; q < 2; ++q) {
            int s = tid + q * 256;
            int r = s >> 2, seg = s & 3;
            *(uint4*)&As[r * 40 + seg * 8] = *(const uint4*)&Ag[(size_t)r * KX + kk + seg * 8];
            *(uint4*)&Bs[r * 40 + seg * 8] = *(const uint4*)&Bg[(size_t)r * KX + kk + seg * 8];
        }
        __syncthreads();
        short8 av[4], bv[4];
#pragma unroll
        for (int i = 0; i < 4; ++i) {
            av[i] = *(const short8*)&As[(wm * 64 + i * 16 + lrow) * 40 + lseg * 8];
            bv[i] = *(const short8*)&Bs[(wn * 64 + i * 16 + lrow) * 40 + lseg * 8];
        }
#pragma unroll
        for (int i = 0; i < 4; ++i)
#pragma unroll
            for (int j = 0; j < 4; ++j)
                acc[i][j] = __builtin_amdgcn_mfma_f32_16x16x32_bf16(bv[j], av[i], acc[i][j],
                                                                    0, 0, 0);
        __syncthreads();
    }
#pragma unroll
    for (int i = 0; i < 4; ++i) {
        const int row = mblk * 128 + wm * 64 + i * 16 + lrow;
        float* orow = xg + (size_t)row * XGS;
#pragma unroll
        for (int j = 0; j < 4; ++j) {
            const int col = nblk * 128 + wn * 64 + j * 16 + lseg * 4;
            f32x4 v = acc[i][j];
            if (col < 1200) {
                f32x4 bo = *(const f32x4*)&b_ih[col];
                v[0] += bo[0]; v[1] += bo[1]; v[2] += bo[2]; v[3] += bo[3];
            }
            *(f32x4*)&orow[col] = v;
        }
    }
}

// Fused: scan (0..479) + W_out cast (480..607) + gated GEMM (608..4607).
// R13 structure; ONLY change: __launch_bounds__(512, 2) so the GEMM branch's
// 64-VGPR accumulator file fits without scratch spill (R13's ",4" capped VGPR
// at 64 -> spills -> +180MB writes). LDS 78.8KB limits to 2 blocks/CU anyway.
__global__ __launch_bounds__(TPB, 2) void k_fused(const int* __restrict__ parents,
                                                  const u16* __restrict__ Wp16,
                                                  const float* __restrict__ xg,
                                                  const float* __restrict__ b_hh,
                                                  const float* __restrict__ rh,
                                                  u16* __restrict__ hb16,
                                                  const int* __restrict__ lvl_nodes,
                                                  const int* __restrict__ lvl_cnt,
                                                  const int* __restrict__ lvl_start,
                                                  const int* __restrict__ nlev,
                                                  int* __restrict__ lvl_done,
                                                  int* __restrict__ tree_done,
                                                  const float* __restrict__ W_out,
                                                  u16* __restrict__ Bbf,
                                                  int* __restrict__ cast_done,
                                                  const float* __restrict__ b_out,
                                                  float* __restrict__ out) {
    __shared__ __align__(16) char smem[SM_BYTES];
    const int t = threadIdx.x;

    if (blockIdx.x < SCANB) {
        // ---------------- scan ----------------
        u16* Wl = (u16*)(smem + SM_WL);
        u16* hs = (u16*)(smem + SM_HS);
        float* gates = (float*)(smem + SM_GATES);
        float* c_lds = (float*)(smem + SM_CL);
        int* nid_s = (int*)(smem + SM_NID);
        int* par_s = (int*)(smem + SM_PAR);

        const int b = blockIdx.x / NSLICE;
        const int s = blockIdx.x % NSLICE;
        const int lane = t & 63, wv = t >> 6;
        const int lrow = lane & 15, lk = lane >> 4;

        {
            const u64* src = (const u64*)(Wp16 + (size_t)s * NROWS * LDW);
            u64* dst = (u64*)Wl;
            for (int e = t; e < NROWS * LDW / 4; e += TPB) dst[e] = src[e];
        }
        if (t < UPS) c_lds[t] = rh[b * HH + s * UPS + t];
        __syncthreads();

        const int nl = nlev[b];
        for (int l = 0; l < nl; ++l) {
            const int cnt = lvl_cnt[b * NN + l];
            const int start = lvl_start[b * NN + l];
            for (int off = 0; off < cnt; off += GMAXN) {
                const int gc = min(GMAXN, cnt - off);
                if (t < gc) {
                    int i = lvl_nodes[b * NN + start + off + t];
                    nid_s[t] = i;
                    par_s[t] = parents[b * NN + i];
                }
                __syncthreads();
                for (int e = t; e < gc * 80; e += TPB) {
                    const int j = e / 80, q = e - j * 80;
                    const u64* hrow = (const u64*)(hb16 +
                        (size_t)(b * 129 + par_s[j] + 1) * KP);
                    *(u64*)&hs[j * LDW + q * 4] = A_LD(&hrow[q]);
                }
                __syncthreads();
                if (wv < 5) {
                    f32x4 acc = {};
#pragma unroll
                    for (int kk = 0; kk < KP; kk += 32) {
                        short8 av = *(const short8*)&hs[lrow * LDW + kk + lk * 8];
                        short8 bv = *(const short8*)&Wl[(wv * 16 + lrow) * LDW + kk + lk * 8];
                        acc = __builtin_amdgcn_mfma_f32_16x16x32_bf16(av, bv, acc, 0, 0, 0);
                    }
#pragma unroll
                    for (int r = 0; r < 4; ++r)
                        gates[(lk * 4 + r) * 82 + wv * 16 + lrow] = acc[r];
                }
                __syncthreads();
                if (t < 160) {
                    const int j = t / 10, up = t - j * 10;
                    if (j < gc) {
                        const int i = nid_s[j];
                        const int par = par_s[j];
                        const int ul0 = up * 2;
                        const float* gj = gates + j * 82;
                        const float* xgp = xg + (size_t)(b * NN + i) * XGS + s * UPS;
                        const float* bhp = b_hh + s * UPS;
                        float hv[2];
#pragma unroll
                        for (int un = 0; un < 2; ++un) {
                            const int ul = ul0 + un;
                            float gs[4];
#pragma unroll
                            for (int g = 0; g < 4; ++g)
                                gs[g] = gj[g * UPS + ul] + xgp[g * HH + ul] + bhp[g * HH + ul];
                            const float pc = c_lds[(par + 1) * UPS + ul];
                            const float cv = sigm(gs[1]) * pc + sigm(gs[0]) * tanh_f(gs[2]);
                            hv[un] = sigm(gs[3]) * tanh_f(cv);
                            c_lds[(i + 1) * UPS + ul] = cv;
                        }
                        const u32 hp = (u32)f2bf(hv[0]) | ((u32)f2bf(hv[1]) << 16);
                        A_ST((u32*)(hb16 + (size_t)(b * 129 + i + 1) * KP + s * UPS + ul0), hp);
                    }
                }
                __syncthreads();  // drains h publishes (vmcnt0) + LDS reuse safety
            }
            if (l + 1 < nl) {
                if (t == 0) {
                    int* dp = &lvl_done[b * NN + l];
                    const int old = A_ADD(dp, 1);
                    if (old != NSLICE - 1) {
                        while (A_LD(dp) < NSLICE) __builtin_amdgcn_s_sleep(1);
                    }
                }
                __syncthreads();
            }
        }
        if (t == 0) A_ADD(&tree_done[b], 1);
    } else if (blockIdx.x < SCANB + CASTB) {
        // ---------------- W_out -> bf16 cast (published via MALL) ----------------
        const int cb = blockIdx.x - SCANB;
        const int per = NV * KP / 4 / CASTB;  // 20000 u64 per block
        u64* Bq = (u64*)Bbf;
        for (int e = cb * per + t; e < (cb + 1) * per; e += TPB) {
            const int c4 = e * 4;
            const int v = c4 / KP, k = c4 - v * KP;
            const float* wr = W_out + (size_t)v * HH;
            float x0 = 0.f, x1 = 0.f, x2 = 0.f, x3 = 0.f;
            if (k + 0 < HH) x0 = wr[k + 0];
            if (k + 1 < HH) x1 = wr[k + 1];
            if (k + 2 < HH) x2 = wr[k + 2];
            if (k + 3 < HH) x3 = wr[k + 3];
            u64 pk = (u64)f2bf(x0) | ((u64)f2bf(x1) << 16) |
                     ((u64)f2bf(x2) << 32) | ((u64)f2bf(x3) << 48);
            A_ST(&Bq[e], pk);
        }
        __syncthreads();  // drains this block's A_STs before the count
        if (t == 0) A_ADD(cast_done, 1);
    } else {
        // ---------------- gated GEMM (128x256 tile, 8 waves) ----------------
        u16* As = (u16*)smem;                  // 128 x 40
        u16* Bs = (u16*)(smem + 10240);        // 256 x 40
        const int gid = blockIdx.x - SCANB - CASTB;
        const int nblk = gid / NB;             // nblk-major
        const int mblk = gid % NB;             // tree
        if (t == 0) {
            while (A_LD(&tree_done[mblk]) < NSLICE || A_LD(cast_done) < CASTB)
                __builtin_amdgcn_s_sleep(16);
        }
        __syncthreads();
        const int lane = t & 63, wv = t >> 6;
        const int wm = wv >> 2, wn = wv & 3;   // 2x4 waves of 64x64
        const int lrow = lane & 15, lseg = lane >> 4;
        const u16* Ag = hb16 + ((size_t)mblk * 129 + 1) * KP;
        const u16* Bg = Bbf + (size_t)nblk * 256 * KP;
        f32x4 acc[4][4] = {};
        for (int kk = 0; kk < KP; kk += 32) {
            {
                int r = t >> 2, seg = t & 3;
                *(uint4*)&As[r * 40 + seg * 8] = *(const uint4*)&Ag[(size_t)r * KP + kk + seg * 8];
            }
#pragma unroll
            for (int q = 0; q < 2; ++q) {
                int sI = t + q * 512;
                int r = sI >> 2, seg = sI & 3;
                *(uint4*)&Bs[r * 40 + seg * 8] = *(const uint4*)&Bg[(size_t)r * KP + kk + seg * 8];
            }
            __syncthreads();
            short8 av[4], bv[4];
#pragma unroll
            for (int i = 0; i < 4; ++i) {
                av[i] = *(const short8*)&As[(wm * 64 + i * 16 + lrow) * 40 + lseg * 8];
                bv[i] = *(const short8*)&Bs[(wn * 64 + i * 16 + lrow) * 40 + lseg * 8];
            }
#pragma unroll
            for (int i = 0; i < 4; ++i)
#pragma unroll
                for (int j = 0; j < 4; ++j)
                    acc[i][j] = __builtin_amdgcn_mfma_f32_16x16x32_bf16(bv[j], av[i], acc[i][j],
                                                                        0, 0, 0);
            __syncthreads();
        }
        // swapped layout: row = m (lane&15), cols = n base + (lane>>4)*4 + reg
#pragma unroll
        for (int i = 0; i < 4; ++i) {
            const int row = mblk * 128 + wm * 64 + i * 16 + lrow;
            float* orow = out + (size_t)row * NV;
#pragma unroll
            for (int j = 0; j < 4; ++j) {
                const int col = nblk * 256 + wn * 64 + j * 16 + lseg * 4;
                f32x4 v = acc[i][j];
                f32x4 bo = *(const f32x4*)&b_out[col];
                v[0] += bo[0]; v[1] += bo[1]; v[2] += bo[2]; v[3] += bo[3];
                __builtin_nontemporal_store(v, (f32x4*)&orow[col]);
            }
        }
    }
}

extern "C" void kernel_launch(void* const* d_in, const int* in_sizes, int n_in,
                              void* d_out, int out_size, void* d_ws, size_t ws_size,
                              hipStream_t stream) {
    const float* root_hidden = (const float*)d_in[0];
    const int* relations = (const int*)d_in[1];
    const int* prev_words = (const int*)d_in[2];
    const int* parents = (const int*)d_in[3];
    const float* emb = (const float*)d_in[4];
    const float* rel_emb = (const float*)d_in[5];
    const float* W_ih = (const float*)d_in[6];
    const float* W_hh = (const float*)d_in[7];
    const float* b_ih = (const float*)d_in[8];
    const float* b_hh = (const float*)d_in[9];
    const float* W_out = (const float*)d_in[10];
    const float* b_out = (const float*)d_in[11];
    float* out = (float*)d_out;

    float* xg = (float*)d_ws;                      // 4096*1280 f32
    u16* Xbf = (u16*)(xg + 4096 * XGS);            // 4096*352 u16
    u16* Wihp = Xbf + 4096 * KX;                   // 1280*352 u16
    u16* Wp16 = Wihp + 1280 * KX;                  // 15*80*328 u16
    u16* hb16 = Wp16 + NSLICE * NROWS * LDW;       // 1320960 u16
    u16* Bbf = hb16 + 1320960;                     // 10240000 u16
    int* lvl_nodes = (int*)(Bbf + 10240000);       // 4096 i32
    int* lvl_cnt = lvl_nodes + 4096;               // 4096 i32
    int* lvl_start = lvl_cnt + 4096;               // 4096 i32
    int* nlev = lvl_start + 4096;                  // 32 i32 (+pad)
    int* lvl_done = nlev + 64;                     // 4096 i32
    int* tree_done = lvl_done + 4096;              // 32 i32
    int* cast_done = tree_done + 32;               // 16 i32

    k_init<<<128, 256, 0, stream>>>(root_hidden, hb16, lvl_done, tree_done, cast_done);
    k_pack<<<1024, 256, 0, stream>>>(W_ih, W_hh, Wihp, Wp16);
    k_gatherX<<<1024, 256, 0, stream>>>(relations, prev_words, rel_emb, emb, Xbf);
    k_prep<<<1, 64, 0, stream>>>(parents, lvl_nodes, lvl_cnt, lvl_start, nlev);

    k_xgemm<<<dim3(32, 10), 256, 0, stream>>>(Xbf, Wihp, b_ih, xg);

    k_fused<<<dim3(SCANB + CASTB + GEMMB), dim3(TPB), 0, stream>>>(
        parents, Wp16, xg, b_hh, root_hidden, hb16,
        lvl_nodes, lvl_cnt, lvl_start, nlev, lvl_done, tree_done,
        W_out, Bbf, cast_done, b_out, out);
}

// Round 15
// 328.171 us; speedup vs baseline: 1.2337x; 1.2337x over previous
//
#include <hip/hip_runtime.h>
#include <hip/hip_bf16.h>

typedef unsigned short u16;
typedef unsigned int u32;
typedef unsigned long long u64;
typedef __attribute__((ext_vector_type(8))) short short8;
typedef __attribute__((ext_vector_type(4))) float f32x4;

#define NB 32      // trees
#define NN 128     // nodes per tree
#define HH 300     // hidden
#define NV 32000   // vocab
#define KP 320     // padded K; hb16 row stride
#define KX 352     // padded RD+E
#define XGS 1280   // xg row stride

// scan: 32 trees x 15 slices, level-synchronous, MFMA MV (R11/R12 proven)
#define NSLICE 15
#define UPS 20
#define NROWS 80
#define TPBS 320
#define GMAXN 16
#define LDW 328

#define A_LD(p)     __hip_atomic_load((p), __ATOMIC_RELAXED, __HIP_MEMORY_SCOPE_AGENT)
#define A_ST(p, v)  __hip_atomic_store((p), (v), __ATOMIC_RELAXED, __HIP_MEMORY_SCOPE_AGENT)
#define A_ADD(p, v) __hip_atomic_fetch_add((p), (v), __ATOMIC_RELAXED, __HIP_MEMORY_SCOPE_AGENT)

__device__ __forceinline__ float sigm(float x) { return 1.f / (1.f + __expf(-x)); }
__device__ __forceinline__ float tanh_f(float x) {
    float e = __expf(2.f * x);
    return 1.f - 2.f / (e + 1.f);
}
__device__ __forceinline__ u16 f2bf(float f) {
    __hip_bfloat16 b = __float2bfloat16(f);
    return *reinterpret_cast<u16*>(&b);
}
__device__ __forceinline__ void gl_lds16(const u16* gsrc, u16* ldst) {
    __builtin_amdgcn_global_load_lds(
        (const __attribute__((address_space(1))) void*)gsrc,
        (__attribute__((address_space(3))) void*)ldst, 16, 0, 0);
}

// Merged prelude: hb16 init (pad + roots), lvl_done zero, Wihp pack, Wp16 pack,
// Xbf gather, Bbf cast. All grid-stride; one launch replaces four.
__global__ __launch_bounds__(256) void k_prelude(const float* __restrict__ rh,
                                                 const int* __restrict__ relations,
                                                 const int* __restrict__ prev_words,
                                                 const float* __restrict__ rel_emb,
                                                 const float* __restrict__ emb,
                                                 const float* __restrict__ W_ih,
                                                 const float* __restrict__ W_hh,
                                                 const float* __restrict__ W_out,
                                                 u16* __restrict__ hb16,
                                                 int* __restrict__ lvl_done,
                                                 u16* __restrict__ Wihp,
                                                 u16* __restrict__ Wp16,
                                                 u16* __restrict__ Xbf,
                                                 u16* __restrict__ Bbf) {
    const int stride = gridDim.x * blockDim.x;
    const int idx = blockIdx.x * blockDim.x + threadIdx.x;
    for (int e = idx; e < NB * 129 * 20; e += stride) {
        int row = e / 20, c = 300 + (e - row * 20);
        hb16[(size_t)row * KP + c] = 0;
    }
    for (int e = idx; e < NB * HH; e += stride) {
        int b = e / HH, u = e - b * HH;
        hb16[(size_t)(b * 129) * KP + u] = f2bf(rh[e]);
    }
    for (int e = idx; e < NB * NN; e += stride) lvl_done[e] = 0;
    for (int n = idx; n < 1280 * KX; n += stride) {
        int r = n / KX, k = n - r * KX;
        float v = (r < 1200 && k < 350) ? W_ih[r * 350 + k] : 0.f;
        Wihp[n] = f2bf(v);
    }
    for (int m = idx; m < NSLICE * NROWS * LDW; m += stride) {
        int s = m / (NROWS * LDW);
        int rem = m - s * (NROWS * LDW);
        int r = rem / LDW, k = rem - r * LDW;
        int g = r / UPS, ul = r - g * UPS;
        int grow = g * HH + s * UPS + ul;
        float v = (k < HH) ? W_hh[grow * HH + k] : 0.f;
        Wp16[m] = f2bf(v);
    }
    for (int e = idx; e < NB * NN * KX; e += stride) {
        int node = e / KX, c = e - node * KX;
        float v = 0.f;
        if (c < 50) v = rel_emb[relations[node] * 50 + c];
        else if (c < 350) v = emb[(size_t)prev_words[node] * 300 + (c - 50)];
        Xbf[e] = f2bf(v);
    }
    u64* Bq = (u64*)Bbf;
    for (int e = idx; e < NV * KP / 4; e += stride) {
        const int c4 = e * 4;
        const int v = c4 / KP, k = c4 - v * KP;
        const float* wr = W_out + (size_t)v * HH;
        float x0 = (k + 0 < HH) ? wr[k + 0] : 0.f;
        float x1 = (k + 1 < HH) ? wr[k + 1] : 0.f;
        float x2 = (k + 2 < HH) ? wr[k + 2] : 0.f;
        float x3 = (k + 3 < HH) ? wr[k + 3] : 0.f;
        Bq[e] = (u64)f2bf(x0) | ((u64)f2bf(x1) << 16) |
                ((u64)f2bf(x2) << 32) | ((u64)f2bf(x3) << 48);
    }
}

// per-tree level schedule
__global__ void k_prep(const int* __restrict__ parents, int* __restrict__ lvl_nodes,
                       int* __restrict__ lvl_cnt, int* __restrict__ lvl_start,
                       int* __restrict__ nlev) {
    __shared__ int dep[NB][NN];
    __shared__ int cnt[NB][NN];
    __shared__ int st[NB][NN];
    const int t = threadIdx.x;
    if (t < NB) {
        for (int l = 0; l < NN; ++l) cnt[t][l] = 0;
        int md = 0;
        for (int i = 0; i < NN; ++i) {
            int p = parents[t * NN + i];
            int d = (p < 0) ? 0 : dep[t][p] + 1;
            dep[t][i] = d;
            cnt[t][d]++;
            md = max(md, d);
        }
        nlev[t] = md + 1;
        int run = 0;
        for (int l = 0; l < NN; ++l) {
            st[t][l] = run;
            lvl_start[t * NN + l] = run;
            lvl_cnt[t * NN + l] = cnt[t][l];
            run += cnt[t][l];
        }
        for (int i = 0; i < NN; ++i) {
            int d = dep[t][i];
            lvl_nodes[t * NN + st[t][d]] = i;
            st[t][d]++;
        }
    }
}

// xg[4096][1280] = X @ Wihp^T + b_ih (swapped-MFMA epilogue, f32x4 stores)
__global__ __launch_bounds__(256) void k_xgemm(const u16* __restrict__ Xbf,
                                               const u16* __restrict__ Wihp,
                                               const float* __restrict__ b_ih,
                                               float* __restrict__ xg) {
    __shared__ __align__(16) u16 As[128 * 40];
    __shared__ __align__(16) u16 Bs[128 * 40];
    const int tid = threadIdx.x;
    const int lane = tid & 63, wv = tid >> 6;
    const int wm = wv >> 1, wn = wv & 1;
    const int mblk = blockIdx.x, nblk = blockIdx.y;
    const u16* Ag = Xbf + (size_t)mblk * 128 * KX;
    const u16* Bg = Wihp + (size_t)nblk * 128 * KX;
    f32x4 acc[4][4] = {};
    const int lrow = lane & 15, lseg = lane >> 4;
    for (int kk = 0; kk < KX; kk += 32) {
#pragma unroll
        for (int q = 0; q < 2; ++q) {
            int s = tid + q * 256;
            int r = s >> 2, seg = s & 3;
            *(uint4*)&As[r * 40 + seg * 8] = *(const uint4*)&Ag[(size_t)r * KX + kk + seg * 8];
            *(uint4*)&Bs[r * 40 + seg * 8] = *(const uint4*)&Bg[(size_t)r * KX + kk + seg * 8];
        }
        __syncthreads();
        short8 av[4], bv[4];
#pragma unroll
        for (int i = 0; i < 4; ++i) {
            av[i] = *(const short8*)&As[(wm * 64 + i * 16 + lrow) * 40 + lseg * 8];
            bv[i] = *(const short8*)&Bs[(wn * 64 + i * 16 + lrow) * 40 + lseg * 8];
        }
#pragma unroll
        for (int i = 0; i < 4; ++i)
#pragma unroll
            for (int j = 0; j < 4; ++j)
                acc[i][j] = __builtin_amdgcn_mfma_f32_16x16x32_bf16(bv[j], av[i], acc[i][j],
                                                                    0, 0, 0);
        __syncthreads();
    }
#pragma unroll
    for (int i = 0; i < 4; ++i) {
        const int row = mblk * 128 + wm * 64 + i * 16 + lrow;
        float* orow = xg + (size_t)row * XGS;
#pragma unroll
        for (int j = 0; j < 4; ++j) {
            const int col = nblk * 128 + wn * 64 + j * 16 + lseg * 4;
            f32x4 v = acc[i][j];
            if (col < 1200) {
                f32x4 bo = *(const f32x4*)&b_ih[col];
                v[0] += bo[0]; v[1] += bo[1]; v[2] += bo[2]; v[3] += bo[3];
            }
            *(f32x4*)&orow[col] = v;
        }
    }
}

// Level-synchronous MFMA scan (R11/R12 proven, byte-identical)
__global__ __launch_bounds__(TPBS) void k_scan(const int* __restrict__ parents,
                                               const u16* __restrict__ Wp16,
                                               const float* __restrict__ xg,
                                               const float* __restrict__ b_hh,
                                               const float* __restrict__ rh,
                                               u16* __restrict__ hb16,
                                               const int* __restrict__ lvl_nodes,
                                               const int* __restrict__ lvl_cnt,
                                               const int* __restrict__ lvl_start,
                                               const int* __restrict__ nlev,
                                               int* __restrict__ lvl_done) {
    __shared__ __align__(16) u16 Wl[NROWS * LDW];
    __shared__ __align__(16) u16 hs[GMAXN * LDW];
    __shared__ __align__(16) float gates[GMAXN * 82];
    __shared__ float c_lds[129 * UPS];
    __shared__ int nid_s[GMAXN], par_s[GMAXN];

    const int t = threadIdx.x;
    const int b = blockIdx.x / NSLICE;
    const int s = blockIdx.x % NSLICE;
    const int lane = t & 63, wv = t >> 6;
    const int lrow = lane & 15, lk = lane >> 4;

    {
        const u64* src = (const u64*)(Wp16 + (size_t)s * NROWS * LDW);
        u64* dst = (u64*)Wl;
        for (int e = t; e < NROWS * LDW / 4; e += TPBS) dst[e] = src[e];
    }
    if (t < UPS) c_lds[t] = rh[b * HH + s * UPS + t];
    __syncthreads();

    const int nl = nlev[b];
    for (int l = 0; l < nl; ++l) {
        const int cnt = lvl_cnt[b * NN + l];
        const int start = lvl_start[b * NN + l];
        for (int off = 0; off < cnt; off += GMAXN) {
            const int gc = min(GMAXN, cnt - off);
            if (t < gc) {
                int i = lvl_nodes[b * NN + start + off + t];
                nid_s[t] = i;
                par_s[t] = parents[b * NN + i];
            }
            __syncthreads();
            for (int e = t; e < gc * 80; e += TPBS) {
                const int j = e / 80, q = e - j * 80;
                const u64* hrow = (const u64*)(hb16 +
                    (size_t)(b * 129 + par_s[j] + 1) * KP);
                *(u64*)&hs[j * LDW + q * 4] = A_LD(&hrow[q]);
            }
            __syncthreads();
            {
                f32x4 acc = {};
#pragma unroll
                for (int kk = 0; kk < KP; kk += 32) {
                    short8 av = *(const short8*)&hs[lrow * LDW + kk + lk * 8];
                    short8 bv = *(const short8*)&Wl[(wv * 16 + lrow) * LDW + kk + lk * 8];
                    acc = __builtin_amdgcn_mfma_f32_16x16x32_bf16(av, bv, acc, 0, 0, 0);
                }
#pragma unroll
                for (int r = 0; r < 4; ++r)
                    gates[(lk * 4 + r) * 82 + wv * 16 + lrow] = acc[r];
            }
            __syncthreads();
            if (t < 160) {
                const int j = t / 10, up = t - j * 10;
                if (j < gc) {
                    const int i = nid_s[j];
                    const int par = par_s[j];
                    const int ul0 = up * 2;
                    const float* gj = gates + j * 82;
                    const float* xgp = xg + (size_t)(b * NN + i) * XGS + s * UPS;
                    const float* bhp = b_hh + s * UPS;
                    float hv[2];
#pragma unroll
                    for (int un = 0; un < 2; ++un) {
                        const int ul = ul0 + un;
                        float gs[4];
#pragma unroll
                        for (int g = 0; g < 4; ++g)
                            gs[g] = gj[g * UPS + ul] + xgp[g * HH + ul] + bhp[g * HH + ul];
                        const float pc = c_lds[(par + 1) * UPS + ul];
                        const float cv = sigm(gs[1]) * pc + sigm(gs[0]) * tanh_f(gs[2]);
                        hv[un] = sigm(gs[3]) * tanh_f(cv);
                        c_lds[(i + 1) * UPS + ul] = cv;
                    }
                    const u32 hp = (u32)f2bf(hv[0]) | ((u32)f2bf(hv[1]) << 16);
                    A_ST((u32*)(hb16 + (size_t)(b * 129 + i + 1) * KP + s * UPS + ul0), hp);
                }
            }
            __syncthreads();
        }
        if (l + 1 < nl) {
            if (t == 0) {
                int* dp = &lvl_done[b * NN + l];
                const int old = A_ADD(dp, 1);
                if (old != NSLICE - 1) {
                    while (A_LD(dp) < NSLICE) __builtin_amdgcn_s_sleep(1);
                }
            }
            __syncthreads();
        }
    }
}

// logits = A(hb16) @ B^T + b_out. global_load_lds staging (width 16) with
// both-sides swizzle: linear LDS [128][32]u16, chunk (r,lk) at quad
// q=(lk+(r>>1))&3 (pre-swizzled per-lane global src; same XOR on reads).
// Swapped-MFMA epilogue -> f32x4 nontemporal stores; XCD-swizzled 1D grid.
__global__ __launch_bounds__(256) void k_gemm(const u16* __restrict__ hb16,
                                              const u16* __restrict__ Bbf,
                                              const float* __restrict__ b_out,
                                              float* __restrict__ out) {
    __shared__ __align__(16) u16 As[128 * 32];
    __shared__ __align__(16) u16 Bs[128 * 32];
    const int tid = threadIdx.x;
    const int lane = tid & 63, wv = tid >> 6;
    const int wm = wv >> 1, wn = wv & 1;
    const int bid = blockIdx.x;                  // 8000 = 32 mblk x 250 nblk
    const int newbid = (bid & 7) * 1000 + (bid >> 3);
    const int mblk = newbid & 31, nblk = newbid >> 5;
    const u16* Ag = hb16 + ((size_t)mblk * 129 + 1) * KP;
    const u16* Bg = Bbf + (size_t)nblk * 128 * KP;
    // staging: wave wv covers rows [wv*32, wv*32+32), 2 insts x 16 rows each
    const int r0 = wv * 32 + (lane >> 2);
    const int r1 = r0 + 16;
    const int q0 = lane & 3;
    const int lk0 = (q0 - (r0 >> 1)) & 3;
    const int lk1 = (q0 - (r1 >> 1)) & 3;
    const u16* pa0 = Ag + (size_t)r0 * KP + lk0 * 8;
    const u16* pa1 = Ag + (size_t)r1 * KP + lk1 * 8;
    const u16* pb0 = Bg + (size_t)r0 * KP + lk0 * 8;
    const u16* pb1 = Bg + (size_t)r1 * KP + lk1 * 8;
    u16* lA = As + wv * 1024;   // 2048 B per wave
    u16* lB = Bs + wv * 1024;
    f32x4 acc[4][4] = {};
    const int lrow = lane & 15, lseg = lane >> 4;
    for (int kk = 0; kk < KP; kk += 32) {
        gl_lds16(pa0 + kk, lA);
        gl_lds16(pa1 + kk, lA + 512);
        gl_lds16(pb0 + kk, lB);
        gl_lds16(pb1 + kk, lB + 512);
        __syncthreads();   // drains vmcnt (global_load_lds) for all waves
        short8 av[4], bv[4];
#pragma unroll
        for (int i = 0; i < 4; ++i) {
            const int ra = wm * 64 + i * 16 + lrow;
            const int rb = wn * 64 + i * 16 + lrow;
            av[i] = *(const short8*)&As[ra * 32 + (((lseg + (ra >> 1)) & 3) * 8)];
            bv[i] = *(const short8*)&Bs[rb * 32 + (((lseg + (rb >> 1)) & 3) * 8)];
        }
#pragma unroll
        for (int i = 0; i < 4; ++i)
#pragma unroll
            for (int j = 0; j < 4; ++j)
                acc[i][j] = __builtin_amdgcn_mfma_f32_16x16x32_bf16(bv[j], av[i], acc[i][j],
                                                                    0, 0, 0);
        __syncthreads();
    }
    // swapped layout: row = m (lane&15), cols = n base + (lane>>4)*4 + reg
#pragma unroll
    for (int i = 0; i < 4; ++i) {
        const int row = mblk * 128 + wm * 64 + i * 16 + lrow;
        float* orow = out + (size_t)row * NV;
#pragma unroll
        for (int j = 0; j < 4; ++j) {
            const int col = nblk * 128 + wn * 64 + j * 16 + lseg * 4;
            f32x4 v = acc[i][j];
            f32x4 bo = *(const f32x4*)&b_out[col];
            v[0] += bo[0]; v[1] += bo[1]; v[2] += bo[2]; v[3] += bo[3];
            __builtin_nontemporal_store(v, (f32x4*)&orow[col]);
        }
    }
}

extern "C" void kernel_launch(void* const* d_in, const int* in_sizes, int n_in,
                              void* d_out, int out_size, void* d_ws, size_t ws_size,
                              hipStream_t stream) {
    const float* root_hidden = (const float*)d_in[0];
    const int* relations = (const int*)d_in[1];
    const int* prev_words = (const int*)d_in[2];
    const int* parents = (const int*)d_in[3];
    const float* emb = (const float*)d_in[4];
    const float* rel_emb = (const float*)d_in[5];
    const float* W_ih = (const float*)d_in[6];
    const float* W_hh = (const float*)d_in[7];
    const float* b_ih = (const float*)d_in[8];
    const float* b_hh = (const float*)d_in[9];
    const float* W_out = (const float*)d_in[10];
    const float* b_out = (const float*)d_in[11];
    float* out = (float*)d_out;

    float* xg = (float*)d_ws;                      // 4096*1280 f32
    u16* Xbf = (u16*)(xg + 4096 * XGS);            // 4096*352 u16
    u16* Wihp = Xbf + 4096 * KX;                   // 1280*352 u16
    u16* Wp16 = Wihp + 1280 * KX;                  // 15*80*328 u16
    u16* hb16 = Wp16 + NSLICE * NROWS * LDW;       // 1320960 u16
    u16* Bbf = hb16 + 1320960;                     // 10240000 u16
    int* lvl_nodes = (int*)(Bbf + 10240000);       // 4096 i32
    int* lvl_cnt = lvl_nodes + 4096;               // 4096 i32
    int* lvl_start = lvl_cnt + 4096;               // 4096 i32
    int* nlev = lvl_start + 4096;                  // 32 i32 (+pad)
    int* lvl_done = nlev + 64;                     // 4096 i32

    k_prelude<<<2048, 256, 0, stream>>>(root_hidden, relations, prev_words, rel_emb, emb,
                                        W_ih, W_hh, W_out, hb16, lvl_done, Wihp, Wp16,
                                        Xbf, Bbf);
    k_prep<<<1, 64, 0, stream>>>(parents, lvl_nodes, lvl_cnt, lvl_start, nlev);

    k_xgemm<<<dim3(32, 10), 256, 0, stream>>>(Xbf, Wihp, b_ih, xg);

    k_scan<<<dim3(NB * NSLICE), dim3(TPBS), 0, stream>>>(
        parents, Wp16, xg, b_hh, root_hidden, hb16,
        lvl_nodes, lvl_cnt, lvl_start, nlev, lvl_done);

    k_gemm<<<dim3(8000), 256, 0, stream>>>(hb16, Bbf, b_out, out);
}